// Round 11
// baseline (362.823 us; speedup 1.0000x reference)
//
#include <hip/hip_runtime.h>
#include <hip/hip_bf16.h>
#include <hip/hip_fp8.h>

#define N_ROWS 4096
#define IN_DIM 768
#define OUT_DIM 512

// All operands fragment-major, all GEMMs barrier-free in the K-loop (no LDS
// staging). Fragment-major (R rows, K cols): unit = gt*(K/32)+kf (gt=row>>4,
// kf=k>>5), byte addr = (unit*64+lane)*16; lane elems: row = gt*16+(lane&15),
// k = kf*32+(lane>>4)*8+j. bf16: 8 elems/lane; fp8: 16 = 2 frags (lo=even kf).
// R11: gemm1/gemm2 full-width 64x512 blocks (A read once); BN fused into
// gemm2 A-frag load; l2norm+fp8 conversion fused into gemm2 epilogue via an
// LDS transpose (barriers only in epilogue). Gram unchanged from R10.

using bf16x8 = __attribute__((ext_vector_type(8))) short;
using f32x4  = __attribute__((ext_vector_type(4))) float;
using i64    = long;
using i64x2  = __attribute__((ext_vector_type(2))) long;

__device__ __constant__ int c_docmap[6] = {0, 1, 0, 2, 1, 2};

__device__ inline unsigned short f2bf(float f) {
    __hip_bfloat16 h = __float2bfloat16(f);
    return reinterpret_cast<unsigned short&>(h);
}
__device__ inline unsigned char f2fp8(float f) {
    __hip_fp8_e4m3 t(f);           // OCP e4m3fn, RNE+sat
    return t.__x;
}
__device__ inline uint4 pack8bf(const float* v) {
    uint4 o;
    unsigned short* p = (unsigned short*)&o;
#pragma unroll
    for (int j = 0; j < 8; ++j) p[j] = f2bf(v[j]);
    return o;
}

// ---------------- prep: conversions to fragment-major + zero-init ----------------
// wave-units: [0,18432) docs; [18432,23040) W1; [23040,26112) W2;
// [26112,26232) zero stats+rowsum (122880 B = 120 units).
__global__ __launch_bounds__(256) void prep(
    const float* __restrict__ d0, const float* __restrict__ d1,
    const float* __restrict__ d2, const float* __restrict__ W1s,
    const float* __restrict__ W2s, unsigned short* __restrict__ Xb,
    unsigned short* __restrict__ W1t, unsigned short* __restrict__ W2t,
    char* __restrict__ zbase) {
    int wunit = blockIdx.x * 4 + (threadIdx.x >> 6);
    int lane = threadIdx.x & 63;
    int lane15 = lane & 15, quad = lane >> 4;
    if (wunit < 18432) {
        int d = wunit / 6144, u = wunit % 6144;       // 256 gt x 24 kf
        int gt = u / 24, kf = u % 24;
        const float* src = (d == 0) ? d0 : ((d == 1) ? d1 : d2);
        const float* s = src + (size_t)(gt * 16 + lane15) * IN_DIM + kf * 32 + quad * 8;
        float4 a = *(const float4*)s, b = *(const float4*)(s + 4);
        float v[8] = {a.x, a.y, a.z, a.w, b.x, b.y, b.z, b.w};
        *(uint4*)(Xb + (size_t)d * N_ROWS * IN_DIM + (size_t)u * 512 + lane * 8) = pack8bf(v);
    } else if (wunit < 23040) {
        int v0 = wunit - 18432;
        int z = v0 / 768, u = v0 % 768;               // 32 gt x 24 kf
        int gt = u / 24, kf = u % 24;
        int n = gt * 16 + lane15;
        int k0 = kf * 32 + quad * 8;
        const float* W = W1s + (size_t)z * IN_DIM * OUT_DIM;
        float v[8];
#pragma unroll
        for (int j = 0; j < 8; ++j) v[j] = W[(size_t)(k0 + j) * OUT_DIM + n];
        *(uint4*)(W1t + (size_t)z * OUT_DIM * IN_DIM + (size_t)u * 512 + lane * 8) = pack8bf(v);
    } else if (wunit < 26112) {
        int v0 = wunit - 23040;
        int z = v0 / 512, u = v0 % 512;               // 32 gt x 16 kf
        int gt = u / 16, kf = u % 16;
        int n = gt * 16 + lane15;
        int k0 = kf * 32 + quad * 8;
        const float* W = W2s + (size_t)z * OUT_DIM * OUT_DIM;
        float v[8];
#pragma unroll
        for (int j = 0; j < 8; ++j) v[j] = W[(size_t)(k0 + j) * OUT_DIM + n];
        *(uint4*)(W2t + (size_t)z * OUT_DIM * OUT_DIM + (size_t)u * 512 + lane * 8) = pack8bf(v);
    } else {
        size_t b = (size_t)(wunit - 26112) * 1024 + (size_t)lane * 16;
        if (b < (size_t)(24576 + 98304))
            *(float4*)(zbase + b) = (float4){0.f, 0.f, 0.f, 0.f};
    }
}

// ---------------- GEMM1: 64x512 full-width, barrier-free, fused BN-stats ----------------
// 512 thr = 8 waves, wave w covers cols w*64..+64; A row-tile read once.
__global__ __launch_bounds__(512) void gemm1_bn(
    const unsigned short* __restrict__ Xb, const unsigned short* __restrict__ W1t,
    const float* __restrict__ biasAll, float* __restrict__ H,
    float* __restrict__ stats) {
    const int NKF = IN_DIM / 32;   // 24
    int z = blockIdx.y;
    int m0 = blockIdx.x * 64;
    const unsigned short* A = Xb + (size_t)c_docmap[z] * N_ROWS * IN_DIM;
    const unsigned short* B = W1t + (size_t)z * OUT_DIM * IN_DIM;
    const float* bz = biasAll + (size_t)z * OUT_DIM;
    float* C = H + (size_t)z * N_ROWS * OUT_DIM;

    int tid = threadIdx.x;
    int wave = tid >> 6, lane = tid & 63;
    int lane15 = lane & 15, quad = lane >> 4;
    int wcol = wave * 64;

    const unsigned short* Ca = A + (size_t)(m0 >> 4) * NKF * 512 + (size_t)lane * 8;
    const unsigned short* Cb = B + (size_t)(wave * 4) * NKF * 512 + (size_t)lane * 8;

    f32x4 acc[4][4];
#pragma unroll
    for (int mt = 0; mt < 4; ++mt)
#pragma unroll
        for (int nt = 0; nt < 4; ++nt)
            acc[mt][nt] = (f32x4){0.f, 0.f, 0.f, 0.f};

    bf16x8 aC[4], bC[4], aN[4], bN[4];
#pragma unroll
    for (int t = 0; t < 4; ++t) {
        aC[t] = *(const bf16x8*)(Ca + (size_t)t * NKF * 512);
        bC[t] = *(const bf16x8*)(Cb + (size_t)t * NKF * 512);
    }
#pragma unroll
    for (int kf = 0; kf < NKF; ++kf) {
        if (kf < NKF - 1) {
#pragma unroll
            for (int t = 0; t < 4; ++t) {
                aN[t] = *(const bf16x8*)(Ca + (size_t)t * NKF * 512 + (kf + 1) * 512);
                bN[t] = *(const bf16x8*)(Cb + (size_t)t * NKF * 512 + (kf + 1) * 512);
            }
        }
#pragma unroll
        for (int mt = 0; mt < 4; ++mt)
#pragma unroll
            for (int nt = 0; nt < 4; ++nt)
                acc[mt][nt] = __builtin_amdgcn_mfma_f32_16x16x32_bf16(aC[mt], bC[nt], acc[mt][nt], 0, 0, 0);
#pragma unroll
        for (int t = 0; t < 4; ++t) { aC[t] = aN[t]; bC[t] = bN[t]; }
    }

    float s1[4] = {0.f, 0.f, 0.f, 0.f}, s2[4] = {0.f, 0.f, 0.f, 0.f};
#pragma unroll
    for (int nt = 0; nt < 4; ++nt) {
        int col = wcol + nt * 16 + lane15;
        float bv = bz[col];
#pragma unroll
        for (int mt = 0; mt < 4; ++mt)
#pragma unroll
            for (int r = 0; r < 4; ++r) {
                int row = m0 + mt * 16 + quad * 4 + r;
                float v = acc[mt][nt][r] + bv;
                C[(size_t)row * OUT_DIM + col] = v;
                s1[nt] += v; s2[nt] += v * v;
            }
    }
#pragma unroll
    for (int nt = 0; nt < 4; ++nt) {
        float a = s1[nt], b = s2[nt];
        a += __shfl_xor(a, 16); a += __shfl_xor(a, 32);
        b += __shfl_xor(b, 16); b += __shfl_xor(b, 32);
        if (quad == 0) {
            int col = wcol + nt * 16 + lane15;
            atomicAdd(&stats[((size_t)z * OUT_DIM + col) * 2 + 0], a);
            atomicAdd(&stats[((size_t)z * OUT_DIM + col) * 2 + 1], b);
        }
    }
}

// ---------------- bn_coef: stats -> (scale, shift) per channel ----------------
// v_bn = relu(v*scale + shift); scale = g*rsig, shift = b - mu*g*rsig.
__global__ void bn_coef(const float* __restrict__ stats, const float* __restrict__ gammas,
                        const float* __restrict__ betas, float* __restrict__ bnc) {
    int i = blockIdx.x * 256 + threadIdx.x;
    if (i >= 6 * OUT_DIM) return;
    int z = i >> 9, c = i & 511;
    float mu = stats[(size_t)i * 2 + 0] * (1.f / N_ROWS);
    float var = stats[(size_t)i * 2 + 1] * (1.f / N_ROWS) - mu * mu;
    float sc = gammas[i] * rsqrtf(var + 1e-5f);
    bnc[(size_t)z * 1024 + c] = sc;
    bnc[(size_t)z * 1024 + 512 + c] = betas[i] - mu * sc;
}

// ---------------- GEMM2 fused: BN(A) inline + bias + l2norm + fp8 frag out ----------------
// 64 rows x 512 cols per block (full width -> complete rows). A = H fp32
// row-major with BN+ReLU+cvt applied at frag-load time. Epilogue: row sumsq
// via LDS cross-wave reduce, normalize, fp8 convert, LDS transpose
// (C-layout -> A-frag-layout), coalesced frag-major store to Abuf.
__global__ __launch_bounds__(512) void gemm2_fused(
    const float* __restrict__ H, const unsigned short* __restrict__ W2t,
    const float* __restrict__ bnc, const float* __restrict__ biasAll,
    unsigned char* __restrict__ Abuf) {
    const int NKF = OUT_DIM / 32;  // 16
    int z = blockIdx.y;
    int m0 = blockIdx.x * 64;
    const float* A = H + (size_t)z * N_ROWS * OUT_DIM;
    const unsigned short* B = W2t + (size_t)z * OUT_DIM * OUT_DIM;
    const float* scp = bnc + (size_t)z * 1024;
    const float* shp = bnc + (size_t)z * 1024 + 512;
    const float* bz = biasAll + (size_t)z * OUT_DIM;
    unsigned char* Az = Abuf + (size_t)z * N_ROWS * OUT_DIM;

    int tid = threadIdx.x;
    int wave = tid >> 6, lane = tid & 63;
    int lane15 = lane & 15, quad = lane >> 4;
    int wcol = wave * 64;

    const float* Ap[4];
#pragma unroll
    for (int mt = 0; mt < 4; ++mt)
        Ap[mt] = A + (size_t)(m0 + mt * 16 + lane15) * OUT_DIM + quad * 8;
    const unsigned short* Cb = B + (size_t)(wave * 4) * NKF * 512 + (size_t)lane * 8;

    f32x4 acc[4][4];
#pragma unroll
    for (int mt = 0; mt < 4; ++mt)
#pragma unroll
        for (int nt = 0; nt < 4; ++nt)
            acc[mt][nt] = (f32x4){0.f, 0.f, 0.f, 0.f};

    float4 aR0[4], aR1[4], nR0[4], nR1[4];
    bf16x8 bC[4], bN[4];
#pragma unroll
    for (int t = 0; t < 4; ++t) {
        aR0[t] = *(const float4*)(Ap[t]);
        aR1[t] = *(const float4*)(Ap[t] + 4);
        bC[t] = *(const bf16x8*)(Cb + (size_t)t * NKF * 512);
    }

#pragma unroll
    for (int kf = 0; kf < NKF; ++kf) {
        if (kf < NKF - 1) {
#pragma unroll
            for (int t = 0; t < 4; ++t) {
                nR0[t] = *(const float4*)(Ap[t] + (kf + 1) * 32);
                nR1[t] = *(const float4*)(Ap[t] + (kf + 1) * 32 + 4);
                bN[t] = *(const bf16x8*)(Cb + (size_t)t * NKF * 512 + (kf + 1) * 512);
            }
        }
        int k0 = kf * 32 + quad * 8;
        float4 sc0 = *(const float4*)(scp + k0), sc1 = *(const float4*)(scp + k0 + 4);
        float4 sh0 = *(const float4*)(shp + k0), sh1 = *(const float4*)(shp + k0 + 4);
        bf16x8 aF[4];
#pragma unroll
        for (int mt = 0; mt < 4; ++mt) {
            float v[8];
            v[0] = fmaxf(fmaf(aR0[mt].x, sc0.x, sh0.x), 0.f);
            v[1] = fmaxf(fmaf(aR0[mt].y, sc0.y, sh0.y), 0.f);
            v[2] = fmaxf(fmaf(aR0[mt].z, sc0.z, sh0.z), 0.f);
            v[3] = fmaxf(fmaf(aR0[mt].w, sc0.w, sh0.w), 0.f);
            v[4] = fmaxf(fmaf(aR1[mt].x, sc1.x, sh1.x), 0.f);
            v[5] = fmaxf(fmaf(aR1[mt].y, sc1.y, sh1.y), 0.f);
            v[6] = fmaxf(fmaf(aR1[mt].z, sc1.z, sh1.z), 0.f);
            v[7] = fmaxf(fmaf(aR1[mt].w, sc1.w, sh1.w), 0.f);
            uint4 pk = pack8bf(v);
            aF[mt] = reinterpret_cast<bf16x8&>(pk);
        }
#pragma unroll
        for (int mt = 0; mt < 4; ++mt)
#pragma unroll
            for (int nt = 0; nt < 4; ++nt)
                acc[mt][nt] = __builtin_amdgcn_mfma_f32_16x16x32_bf16(aF[mt], bC[nt], acc[mt][nt], 0, 0, 0);
#pragma unroll
        for (int t = 0; t < 4; ++t) { aR0[t] = nR0[t]; aR1[t] = nR1[t]; bC[t] = bN[t]; }
    }

    // ---- epilogue: bias, row sumsq, normalize, fp8, transpose, store ----
    __shared__ float part[8][64];
    __shared__ float scf[64];
    __shared__ __attribute__((aligned(16))) unsigned char T[64 * 520];

    // bias add in place + per-lane row partials (rows mt*16+quad*4+r)
    float rs[16];
#pragma unroll
    for (int j = 0; j < 16; ++j) rs[j] = 0.f;
#pragma unroll
    for (int nt = 0; nt < 4; ++nt) {
        float bv = bz[wcol + nt * 16 + lane15];
#pragma unroll
        for (int mt = 0; mt < 4; ++mt)
#pragma unroll
            for (int r = 0; r < 4; ++r) {
                float v = acc[mt][nt][r] + bv;
                acc[mt][nt][r] = v;
                rs[mt * 4 + r] += v * v;
            }
    }
#pragma unroll
    for (int j = 0; j < 16; ++j) {
        float v = rs[j];
        v += __shfl_xor(v, 1); v += __shfl_xor(v, 2);
        v += __shfl_xor(v, 4); v += __shfl_xor(v, 8);
        rs[j] = v;
    }
    if (lane15 == 0) {
#pragma unroll
        for (int j = 0; j < 16; ++j)
            part[wave][(j >> 2) * 16 + quad * 4 + (j & 3)] = rs[j];
    }
    __syncthreads();
    if (tid < 64) {
        float ss = 0.f;
#pragma unroll
        for (int w = 0; w < 8; ++w) ss += part[w][tid];
        scf[tid] = 1.f / fmaxf(sqrtf(ss), 1e-12f);
    }
    __syncthreads();
    // normalized fp8 bytes into LDS transpose buffer (row-major, stride 520)
#pragma unroll
    for (int mt = 0; mt < 4; ++mt)
#pragma unroll
        for (int r = 0; r < 4; ++r) {
            int row = mt * 16 + quad * 4 + r;
            float s = scf[row];
#pragma unroll
            for (int nt = 0; nt < 4; ++nt)
                T[row * 520 + wcol + nt * 16 + lane15] = f2fp8(acc[mt][nt][r] * s);
        }
    __syncthreads();
    // readback A-frag-major: wave = kh, lane's 16 B = frags kf=2kh (lo), 2kh+1 (hi)
#pragma unroll
    for (int gt = 0; gt < 4; ++gt) {
        int row = gt * 16 + lane15;
        i64 lo = *(const i64*)(T + row * 520 + (2 * wave) * 32 + quad * 8);
        i64 hi = *(const i64*)(T + row * 520 + (2 * wave + 1) * 32 + quad * 8);
        i64x2 st; st[0] = lo; st[1] = hi;
        int gtg = (m0 >> 4) + gt;
        *(i64x2*)(Az + ((size_t)(gtg * 8 + wave) * 64 + lane) * 16) = st;
    }
}

// ---------------- barrier-free fp8 Gram: 256x128 supertile, J>=2I masked ----------------
__global__ __launch_bounds__(512) void gram_kernel(const unsigned char* __restrict__ Abase,
                                                   float* __restrict__ rowsum,
                                                   float* __restrict__ crossdot) {
    int px = blockIdx.x;
    int logical = (px & 7) * 396 + (px >> 3);     // 3168 = 8 * 396
    int p = logical / 1056;
    int t0 = logical - p * 1056;
    const unsigned char* Cm = Abase + (size_t)p * 2 * N_ROWS * OUT_DIM;

    int I = 0;
    while (t0 >= 64 - 2 * I) { t0 -= 64 - 2 * I; ++I; }
    int J = 2 * I + t0;
    int m0 = I * 256, n0 = J * 128;

    int tid = threadIdx.x;
    int wave = tid >> 6, lane = tid & 63;
    int lane15 = lane & 15, quad = lane >> 4;
    int wrow = (wave >> 1) * 64, wcol = (wave & 1) * 64;

    const unsigned char* Ca = Cm + (size_t)((m0 + wrow) >> 4) * 8192 + (size_t)lane * 16;
    const unsigned char* Cb = Cm + (size_t)((n0 + wcol) >> 4) * 8192 + (size_t)lane * 16;

    f32x4 acc[4][4];
#pragma unroll
    for (int mt = 0; mt < 4; ++mt)
#pragma unroll
        for (int nt = 0; nt < 4; ++nt)
            acc[mt][nt] = (f32x4){0.f, 0.f, 0.f, 0.f};

    i64x2 aC[4], bC[4], aN[4], bN[4];
#pragma unroll
    for (int t = 0; t < 4; ++t) {
        aC[t] = *(const i64x2*)(Ca + (size_t)t * 8192);
        bC[t] = *(const i64x2*)(Cb + (size_t)t * 8192);
    }
#pragma unroll
    for (int kh = 0; kh < 8; ++kh) {
        if (kh < 7) {
#pragma unroll
            for (int t = 0; t < 4; ++t) {
                aN[t] = *(const i64x2*)(Ca + (size_t)t * 8192 + (kh + 1) * 1024);
                bN[t] = *(const i64x2*)(Cb + (size_t)t * 8192 + (kh + 1) * 1024);
            }
        }
#pragma unroll
        for (int half = 0; half < 2; ++half)
#pragma unroll
            for (int mt = 0; mt < 4; ++mt)
#pragma unroll
                for (int nt = 0; nt < 4; ++nt)
                    acc[mt][nt] = __builtin_amdgcn_mfma_f32_16x16x32_fp8_fp8(
                        aC[mt][half], bC[nt][half], acc[mt][nt], 0, 0, 0);
#pragma unroll
        for (int t = 0; t < 4; ++t) { aC[t] = aN[t]; bC[t] = bN[t]; }
    }

    float* cdp = crossdot + (size_t)p * 2 * N_ROWS;
    float* rp  = rowsum  + (size_t)p * 2 * N_ROWS;

    float rs[16];
    float cs[4] = {0.f, 0.f, 0.f, 0.f};
#pragma unroll
    for (int j = 0; j < 16; ++j) rs[j] = 0.f;

    if (J >= 2 * I + 2) {
#pragma unroll
        for (int mt = 0; mt < 4; ++mt)
#pragma unroll
            for (int nt = 0; nt < 4; ++nt)
#pragma unroll
                for (int r = 0; r < 4; ++r) {
                    float e = __expf(2.f * acc[mt][nt][r]);
                    rs[mt * 4 + r] += e;
                    cs[nt] += e;
                }
        if (J >= 32 && ((J - 32) >> 1) == I) {
#pragma unroll
            for (int mt = 0; mt < 4; ++mt)
#pragma unroll
                for (int nt = 0; nt < 4; ++nt) {
                    int gcol = n0 + wcol + nt * 16 + lane15;
#pragma unroll
                    for (int r = 0; r < 4; ++r) {
                        int grow = m0 + wrow + mt * 16 + quad * 4 + r;
                        if (gcol == grow + N_ROWS) {
                            float s = acc[mt][nt][r];
                            cdp[grow] = s;
                            cdp[gcol] = s;
                        }
                    }
                }
        }
    } else {
#pragma unroll
        for (int mt = 0; mt < 4; ++mt)
#pragma unroll
            for (int nt = 0; nt < 4; ++nt) {
                int gcol = n0 + wcol + nt * 16 + lane15;
#pragma unroll
                for (int r = 0; r < 4; ++r) {
                    int grow = m0 + wrow + mt * 16 + quad * 4 + r;
                    if (grow < gcol) {
                        float e = __expf(2.f * acc[mt][nt][r]);
                        rs[mt * 4 + r] += e;
                        cs[nt] += e;
                    }
                }
            }
    }

#pragma unroll
    for (int j = 0; j < 16; ++j) {
        float v = rs[j];
        v += __shfl_xor(v, 1); v += __shfl_xor(v, 2);
        v += __shfl_xor(v, 4); v += __shfl_xor(v, 8);
        rs[j] = v;
    }
    if (lane15 == 0) {
#pragma unroll
        for (int j = 0; j < 16; ++j) {
            int grow = m0 + wrow + (j >> 2) * 16 + quad * 4 + (j & 3);
            atomicAdd(&rp[grow], rs[j]);
        }
    }
#pragma unroll
    for (int n = 0; n < 4; ++n) {
        float v = cs[n];
        v += __shfl_xor(v, 16); v += __shfl_xor(v, 32);
        cs[n] = v;
    }
    if (quad == 0) {
#pragma unroll
        for (int n = 0; n < 4; ++n) {
            int gcol = n0 + wcol + n * 16 + lane15;
            atomicAdd(&rp[gcol], cs[n]);
        }
    }
}

// ---------------- final loss reduction ----------------
__global__ void loss_kernel(const float* __restrict__ rowsum,
                            const float* __restrict__ crossdot, float* __restrict__ out) {
    __shared__ float red[256];
    float acc = 0.f;
    for (int i = threadIdx.x; i < 3 * 2 * N_ROWS; i += 256) {
        acc += logf(rowsum[i]) - 2.f * crossdot[i];
    }
    red[threadIdx.x] = acc;
    __syncthreads();
    for (int s = 128; s > 0; s >>= 1) {
        if (threadIdx.x < s) red[threadIdx.x] += red[threadIdx.x + s];
        __syncthreads();
    }
    if (threadIdx.x == 0) out[0] = red[0] * (1.f / 24576.f);
}

// ---------------- launch ----------------
extern "C" void kernel_launch(void* const* d_in, const int* in_sizes, int n_in,
                              void* d_out, int out_size, void* d_ws, size_t ws_size,
                              hipStream_t stream) {
    const float* doc0   = (const float*)d_in[0];
    const float* doc1   = (const float*)d_in[1];
    const float* doc2   = (const float*)d_in[2];
    const float* W1s    = (const float*)d_in[3];
    const float* b1s    = (const float*)d_in[4];
    const float* gammas = (const float*)d_in[5];
    const float* betas  = (const float*)d_in[6];
    const float* W2s    = (const float*)d_in[7];
    const float* b2s    = (const float*)d_in[8];
    float* out = (float*)d_out;

    char* base = (char*)d_ws;
    size_t off = 0;
    auto alloc = [&](size_t bytes) -> char* {
        char* r = base + off;
        off += (bytes + 255) & ~(size_t)255;
        return r;
    };

    unsigned short* Xb   = (unsigned short*)alloc((size_t)3 * N_ROWS * IN_DIM * 2);
    unsigned short* W1t  = (unsigned short*)alloc((size_t)6 * OUT_DIM * IN_DIM * 2);
    unsigned short* W2t  = (unsigned short*)alloc((size_t)6 * OUT_DIM * OUT_DIM * 2);
    float*          H    = (float*)         alloc((size_t)6 * N_ROWS * OUT_DIM * 4);
    unsigned char*  Abuf = (unsigned char*)Xb;    // Xb dead after gemm1
    char* zbase = alloc(24576 + 98304);
    float* stats  = (float*)zbase;
    float* rowsum = (float*)(zbase + 24576);
    float* bnc    = (float*)alloc((size_t)6 * 1024 * 4);
    float* cdot   = (float*)alloc((size_t)3 * 2 * N_ROWS * 4);

    if (ws_size < off) return;

    // 26112 conversion wave-units + 120 zero units = 26232 -> 6558 blocks
    prep<<<6558, 256, 0, stream>>>(doc0, doc1, doc2, W1s, W2s, Xb, W1t, W2t, zbase);

    gemm1_bn<<<dim3(64, 6), 512, 0, stream>>>(Xb, W1t, b1s, H, stats);

    bn_coef<<<12, 256, 0, stream>>>(stats, gammas, betas, bnc);

    gemm2_fused<<<dim3(64, 6), 512, 0, stream>>>(H, W2t, bnc, b2s, Abuf);

    // supertile gram: 3 pairs x 1056 (J>=2I) tile-pairs, XCD swizzled
    gram_kernel<<<3168, 512, 0, stream>>>(Abuf, rowsum, cdot);

    loss_kernel<<<1, 256, 0, stream>>>(rowsum, cdot, out);
}

// Round 12
// 330.605 us; speedup vs baseline: 1.0975x; 1.0975x over previous
//
#include <hip/hip_runtime.h>
#include <hip/hip_bf16.h>
#include <hip/hip_fp8.h>

#define N_ROWS 4096
#define IN_DIM 768
#define OUT_DIM 512

// All GEMM operands fragment-major, all K-loops barrier-free (no LDS staging).
// Fragment-major (R rows, K cols): unit = gt*(K/32)+kf (gt=row>>4, kf=k>>5),
// byte addr = (unit*64+lane)*16; lane elems: row = gt*16+(lane&15),
// k = kf*32+(lane>>4)*8+j. bf16: 8 elems/lane; fp8: 16 = 2 frags (lo=even kf).
// R12: BN as standalone pointwise pass (R11's in-loop BN was VALU-bound);
// gemm1 writes bf16 H; gemm2 fuses l2norm+fp8+frag-transpose in EPILOGUE
// (validated R11, absmax 0.0). Gram = R10/R11 (XCD-swizzled supertiles).

using bf16x8 = __attribute__((ext_vector_type(8))) short;
using f32x4  = __attribute__((ext_vector_type(4))) float;
using i64    = long;
using i64x2  = __attribute__((ext_vector_type(2))) long;

__device__ __constant__ int c_docmap[6] = {0, 1, 0, 2, 1, 2};

__device__ inline unsigned short f2bf(float f) {
    __hip_bfloat16 h = __float2bfloat16(f);
    return reinterpret_cast<unsigned short&>(h);
}
__device__ inline float bf2f(unsigned short u) {
    return __uint_as_float((unsigned int)u << 16);
}
__device__ inline unsigned char f2fp8(float f) {
    __hip_fp8_e4m3 t(f);           // OCP e4m3fn, RNE+sat
    return t.__x;
}
__device__ inline uint4 pack8bf(const float* v) {
    uint4 o;
    unsigned short* p = (unsigned short*)&o;
#pragma unroll
    for (int j = 0; j < 8; ++j) p[j] = f2bf(v[j]);
    return o;
}

// ---------------- prep: conversions to fragment-major + zero-init ----------------
__global__ __launch_bounds__(256) void prep(
    const float* __restrict__ d0, const float* __restrict__ d1,
    const float* __restrict__ d2, const float* __restrict__ W1s,
    const float* __restrict__ W2s, unsigned short* __restrict__ Xb,
    unsigned short* __restrict__ W1t, unsigned short* __restrict__ W2t,
    char* __restrict__ zbase) {
    int wunit = blockIdx.x * 4 + (threadIdx.x >> 6);
    int lane = threadIdx.x & 63;
    int lane15 = lane & 15, quad = lane >> 4;
    if (wunit < 18432) {
        int d = wunit / 6144, u = wunit % 6144;       // 256 gt x 24 kf
        int gt = u / 24, kf = u % 24;
        const float* src = (d == 0) ? d0 : ((d == 1) ? d1 : d2);
        const float* s = src + (size_t)(gt * 16 + lane15) * IN_DIM + kf * 32 + quad * 8;
        float4 a = *(const float4*)s, b = *(const float4*)(s + 4);
        float v[8] = {a.x, a.y, a.z, a.w, b.x, b.y, b.z, b.w};
        *(uint4*)(Xb + (size_t)d * N_ROWS * IN_DIM + (size_t)u * 512 + lane * 8) = pack8bf(v);
    } else if (wunit < 23040) {
        int v0 = wunit - 18432;
        int z = v0 / 768, u = v0 % 768;               // 32 gt x 24 kf
        int gt = u / 24, kf = u % 24;
        int n = gt * 16 + lane15;
        int k0 = kf * 32 + quad * 8;
        const float* W = W1s + (size_t)z * IN_DIM * OUT_DIM;
        float v[8];
#pragma unroll
        for (int j = 0; j < 8; ++j) v[j] = W[(size_t)(k0 + j) * OUT_DIM + n];
        *(uint4*)(W1t + (size_t)z * OUT_DIM * IN_DIM + (size_t)u * 512 + lane * 8) = pack8bf(v);
    } else if (wunit < 26112) {
        int v0 = wunit - 23040;
        int z = v0 / 512, u = v0 % 512;               // 32 gt x 16 kf
        int gt = u / 16, kf = u % 16;
        int n = gt * 16 + lane15;
        int k0 = kf * 32 + quad * 8;
        const float* W = W2s + (size_t)z * OUT_DIM * OUT_DIM;
        float v[8];
#pragma unroll
        for (int j = 0; j < 8; ++j) v[j] = W[(size_t)(k0 + j) * OUT_DIM + n];
        *(uint4*)(W2t + (size_t)z * OUT_DIM * OUT_DIM + (size_t)u * 512 + lane * 8) = pack8bf(v);
    } else {
        size_t b = (size_t)(wunit - 26112) * 1024 + (size_t)lane * 16;
        if (b < (size_t)(24576 + 98304))
            *(float4*)(zbase + b) = (float4){0.f, 0.f, 0.f, 0.f};
    }
}

// ---------------- GEMM1: 256x128 supertile, barrier-free, BF16 out + BN-stats ----------------
__global__ __launch_bounds__(512) void gemm1_bn(
    const unsigned short* __restrict__ Xb, const unsigned short* __restrict__ W1t,
    const float* __restrict__ biasAll, unsigned short* __restrict__ H,
    float* __restrict__ stats) {
    const int NKF = IN_DIM / 32;   // 24
    int z = blockIdx.z;
    const unsigned short* A = Xb + (size_t)c_docmap[z] * N_ROWS * IN_DIM;
    const unsigned short* B = W1t + (size_t)z * OUT_DIM * IN_DIM;
    const float* bz = biasAll + (size_t)z * OUT_DIM;
    unsigned short* C = H + (size_t)z * N_ROWS * OUT_DIM;

    int m0 = blockIdx.y * 256, n0 = blockIdx.x * 128;
    int tid = threadIdx.x;
    int wave = tid >> 6, lane = tid & 63;
    int lane15 = lane & 15, quad = lane >> 4;
    int wrow = (wave >> 1) * 64, wcol = (wave & 1) * 64;

    const unsigned short* Ca = A + (size_t)((m0 + wrow) >> 4) * NKF * 512 + (size_t)lane * 8;
    const unsigned short* Cb = B + (size_t)((n0 + wcol) >> 4) * NKF * 512 + (size_t)lane * 8;

    f32x4 acc[4][4];
#pragma unroll
    for (int mt = 0; mt < 4; ++mt)
#pragma unroll
        for (int nt = 0; nt < 4; ++nt)
            acc[mt][nt] = (f32x4){0.f, 0.f, 0.f, 0.f};

    bf16x8 aC[4], bC[4], aN[4], bN[4];
#pragma unroll
    for (int t = 0; t < 4; ++t) {
        aC[t] = *(const bf16x8*)(Ca + (size_t)t * NKF * 512);
        bC[t] = *(const bf16x8*)(Cb + (size_t)t * NKF * 512);
    }
#pragma unroll
    for (int kf = 0; kf < NKF; ++kf) {
        if (kf < NKF - 1) {
#pragma unroll
            for (int t = 0; t < 4; ++t) {
                aN[t] = *(const bf16x8*)(Ca + (size_t)t * NKF * 512 + (kf + 1) * 512);
                bN[t] = *(const bf16x8*)(Cb + (size_t)t * NKF * 512 + (kf + 1) * 512);
            }
        }
#pragma unroll
        for (int mt = 0; mt < 4; ++mt)
#pragma unroll
            for (int nt = 0; nt < 4; ++nt)
                acc[mt][nt] = __builtin_amdgcn_mfma_f32_16x16x32_bf16(aC[mt], bC[nt], acc[mt][nt], 0, 0, 0);
#pragma unroll
        for (int t = 0; t < 4; ++t) { aC[t] = aN[t]; bC[t] = bN[t]; }
    }

    float s1[4] = {0.f, 0.f, 0.f, 0.f}, s2[4] = {0.f, 0.f, 0.f, 0.f};
#pragma unroll
    for (int nt = 0; nt < 4; ++nt) {
        int col = n0 + wcol + nt * 16 + lane15;
        float bv = bz[col];
#pragma unroll
        for (int mt = 0; mt < 4; ++mt)
#pragma unroll
            for (int r = 0; r < 4; ++r) {
                int row = m0 + wrow + mt * 16 + quad * 4 + r;
                float v = acc[mt][nt][r] + bv;
                C[(size_t)row * OUT_DIM + col] = f2bf(v);
                s1[nt] += v; s2[nt] += v * v;       // stats from fp32 (exact)
            }
    }
#pragma unroll
    for (int nt = 0; nt < 4; ++nt) {
        float a = s1[nt], b = s2[nt];
        a += __shfl_xor(a, 16); a += __shfl_xor(a, 32);
        b += __shfl_xor(b, 16); b += __shfl_xor(b, 32);
        if (quad == 0) {
            int col = n0 + wcol + nt * 16 + lane15;
            atomicAdd(&stats[((size_t)z * OUT_DIM + col) * 2 + 0], a);
            atomicAdd(&stats[((size_t)z * OUT_DIM + col) * 2 + 1], b);
        }
    }
}

// ---------------- BN apply + ReLU: bf16 H row-major -> bf16 Hb FRAG-MAJOR ----------------
// wave-units: 6 z x 256 gt x 16 kf = 24576.
__global__ __launch_bounds__(256) void bn_apply(
    const unsigned short* __restrict__ H, unsigned short* __restrict__ Hb,
    const float* __restrict__ stats, const float* __restrict__ gammas,
    const float* __restrict__ betas) {
    int wunit = blockIdx.x * 4 + (threadIdx.x >> 6);
    if (wunit >= 24576) return;
    int lane = threadIdx.x & 63;
    int lane15 = lane & 15, quad = lane >> 4;
    int z = wunit / 4096, u = wunit % 4096;       // 256 gt x 16 kf
    int gt = u / 16, kf = u % 16;
    int row = gt * 16 + lane15;
    int k = kf * 32 + quad * 8;
    uint4 hu = *(const uint4*)(H + ((size_t)z * N_ROWS + row) * OUT_DIM + k);
    unsigned int w[4] = {hu.x, hu.y, hu.z, hu.w};
    float v[8];
#pragma unroll
    for (int j = 0; j < 8; ++j) {
        unsigned short us = (j & 1) ? (unsigned short)(w[j >> 1] >> 16)
                                    : (unsigned short)(w[j >> 1] & 0xffff);
        size_t sc = (size_t)z * OUT_DIM + k + j;
        float mu = stats[sc * 2 + 0] * (1.f / N_ROWS);
        float var = stats[sc * 2 + 1] * (1.f / N_ROWS) - mu * mu;
        float s = gammas[sc] * rsqrtf(var + 1e-5f);
        v[j] = fmaxf(fmaf(bf2f(us), s, betas[sc] - mu * s), 0.f);
    }
    *(uint4*)(Hb + (size_t)z * N_ROWS * OUT_DIM + (size_t)u * 512 + lane * 8) = pack8bf(v);
}

// ---------------- GEMM2 fused: barrier-free K-loop + l2norm/fp8/transpose epilogue ----------------
// 64 rows x 512 cols per block (complete rows). A = Hb bf16 frag-major.
__global__ __launch_bounds__(512) void gemm2_fused(
    const unsigned short* __restrict__ Hb, const unsigned short* __restrict__ W2t,
    const float* __restrict__ biasAll, unsigned char* __restrict__ Abuf) {
    const int NKF = OUT_DIM / 32;  // 16
    int z = blockIdx.y;
    int m0 = blockIdx.x * 64;
    const unsigned short* A = Hb + (size_t)z * N_ROWS * OUT_DIM;
    const unsigned short* B = W2t + (size_t)z * OUT_DIM * OUT_DIM;
    const float* bz = biasAll + (size_t)z * OUT_DIM;
    unsigned char* Az = Abuf + (size_t)z * N_ROWS * OUT_DIM;

    int tid = threadIdx.x;
    int wave = tid >> 6, lane = tid & 63;
    int lane15 = lane & 15, quad = lane >> 4;
    int wcol = wave * 64;

    const unsigned short* Ca = A + (size_t)(m0 >> 4) * NKF * 512 + (size_t)lane * 8;
    const unsigned short* Cb = B + (size_t)(wave * 4) * NKF * 512 + (size_t)lane * 8;

    f32x4 acc[4][4];
#pragma unroll
    for (int mt = 0; mt < 4; ++mt)
#pragma unroll
        for (int nt = 0; nt < 4; ++nt)
            acc[mt][nt] = (f32x4){0.f, 0.f, 0.f, 0.f};

    bf16x8 aC[4], bC[4], aN[4], bN[4];
#pragma unroll
    for (int t = 0; t < 4; ++t) {
        aC[t] = *(const bf16x8*)(Ca + (size_t)t * NKF * 512);
        bC[t] = *(const bf16x8*)(Cb + (size_t)t * NKF * 512);
    }
#pragma unroll
    for (int kf = 0; kf < NKF; ++kf) {
        if (kf < NKF - 1) {
#pragma unroll
            for (int t = 0; t < 4; ++t) {
                aN[t] = *(const bf16x8*)(Ca + (size_t)t * NKF * 512 + (kf + 1) * 512);
                bN[t] = *(const bf16x8*)(Cb + (size_t)t * NKF * 512 + (kf + 1) * 512);
            }
        }
#pragma unroll
        for (int mt = 0; mt < 4; ++mt)
#pragma unroll
            for (int nt = 0; nt < 4; ++nt)
                acc[mt][nt] = __builtin_amdgcn_mfma_f32_16x16x32_bf16(aC[mt], bC[nt], acc[mt][nt], 0, 0, 0);
#pragma unroll
        for (int t = 0; t < 4; ++t) { aC[t] = aN[t]; bC[t] = bN[t]; }
    }

    // ---- epilogue (validated R11): bias, row sumsq, normalize, fp8, transpose ----
    __shared__ float part[8][64];
    __shared__ float scf[64];
    __shared__ __attribute__((aligned(16))) unsigned char T[64 * 520];

    float rs[16];
#pragma unroll
    for (int j = 0; j < 16; ++j) rs[j] = 0.f;
#pragma unroll
    for (int nt = 0; nt < 4; ++nt) {
        float bv = bz[wcol + nt * 16 + lane15];
#pragma unroll
        for (int mt = 0; mt < 4; ++mt)
#pragma unroll
            for (int r = 0; r < 4; ++r) {
                float v = acc[mt][nt][r] + bv;
                acc[mt][nt][r] = v;
                rs[mt * 4 + r] += v * v;
            }
    }
#pragma unroll
    for (int j = 0; j < 16; ++j) {
        float v = rs[j];
        v += __shfl_xor(v, 1); v += __shfl_xor(v, 2);
        v += __shfl_xor(v, 4); v += __shfl_xor(v, 8);
        rs[j] = v;
    }
    if (lane15 == 0) {
#pragma unroll
        for (int j = 0; j < 16; ++j)
            part[wave][(j >> 2) * 16 + quad * 4 + (j & 3)] = rs[j];
    }
    __syncthreads();
    if (tid < 64) {
        float ss = 0.f;
#pragma unroll
        for (int w = 0; w < 8; ++w) ss += part[w][tid];
        scf[tid] = 1.f / fmaxf(sqrtf(ss), 1e-12f);
    }
    __syncthreads();
#pragma unroll
    for (int mt = 0; mt < 4; ++mt)
#pragma unroll
        for (int r = 0; r < 4; ++r) {
            int row = mt * 16 + quad * 4 + r;
            float s = scf[row];
#pragma unroll
            for (int nt = 0; nt < 4; ++nt)
                T[row * 520 + wcol + nt * 16 + lane15] = f2fp8(acc[mt][nt][r] * s);
        }
    __syncthreads();
    // readback A-frag-major: wave = kh, lane's 16 B = frags kf=2kh (lo), 2kh+1 (hi)
#pragma unroll
    for (int gt = 0; gt < 4; ++gt) {
        int row = gt * 16 + lane15;
        i64 lo = *(const i64*)(T + row * 520 + (2 * wave) * 32 + quad * 8);
        i64 hi = *(const i64*)(T + row * 520 + (2 * wave + 1) * 32 + quad * 8);
        i64x2 st; st[0] = lo; st[1] = hi;
        int gtg = (m0 >> 4) + gt;
        *(i64x2*)(Az + ((size_t)(gtg * 8 + wave) * 64 + lane) * 16) = st;
    }
}

// ---------------- barrier-free fp8 Gram: 256x128 supertile, J>=2I masked ----------------
__global__ __launch_bounds__(512) void gram_kernel(const unsigned char* __restrict__ Abase,
                                                   float* __restrict__ rowsum,
                                                   float* __restrict__ crossdot) {
    int px = blockIdx.x;
    int logical = (px & 7) * 396 + (px >> 3);     // 3168 = 8 * 396
    int p = logical / 1056;
    int t0 = logical - p * 1056;
    const unsigned char* Cm = Abase + (size_t)p * 2 * N_ROWS * OUT_DIM;

    int I = 0;
    while (t0 >= 64 - 2 * I) { t0 -= 64 - 2 * I; ++I; }
    int J = 2 * I + t0;
    int m0 = I * 256, n0 = J * 128;

    int tid = threadIdx.x;
    int wave = tid >> 6, lane = tid & 63;
    int lane15 = lane & 15, quad = lane >> 4;
    int wrow = (wave >> 1) * 64, wcol = (wave & 1) * 64;

    const unsigned char* Ca = Cm + (size_t)((m0 + wrow) >> 4) * 8192 + (size_t)lane * 16;
    const unsigned char* Cb = Cm + (size_t)((n0 + wcol) >> 4) * 8192 + (size_t)lane * 16;

    f32x4 acc[4][4];
#pragma unroll
    for (int mt = 0; mt < 4; ++mt)
#pragma unroll
        for (int nt = 0; nt < 4; ++nt)
            acc[mt][nt] = (f32x4){0.f, 0.f, 0.f, 0.f};

    i64x2 aC[4], bC[4], aN[4], bN[4];
#pragma unroll
    for (int t = 0; t < 4; ++t) {
        aC[t] = *(const i64x2*)(Ca + (size_t)t * 8192);
        bC[t] = *(const i64x2*)(Cb + (size_t)t * 8192);
    }
#pragma unroll
    for (int kh = 0; kh < 8; ++kh) {
        if (kh < 7) {
#pragma unroll
            for (int t = 0; t < 4; ++t) {
                aN[t] = *(const i64x2*)(Ca + (size_t)t * 8192 + (kh + 1) * 1024);
                bN[t] = *(const i64x2*)(Cb + (size_t)t * 8192 + (kh + 1) * 1024);
            }
        }
#pragma unroll
        for (int half = 0; half < 2; ++half)
#pragma unroll
            for (int mt = 0; mt < 4; ++mt)
#pragma unroll
                for (int nt = 0; nt < 4; ++nt)
                    acc[mt][nt] = __builtin_amdgcn_mfma_f32_16x16x32_fp8_fp8(
                        aC[mt][half], bC[nt][half], acc[mt][nt], 0, 0, 0);
#pragma unroll
        for (int t = 0; t < 4; ++t) { aC[t] = aN[t]; bC[t] = bN[t]; }
    }

    float* cdp = crossdot + (size_t)p * 2 * N_ROWS;
    float* rp  = rowsum  + (size_t)p * 2 * N_ROWS;

    float rs[16];
    float cs[4] = {0.f, 0.f, 0.f, 0.f};
#pragma unroll
    for (int j = 0; j < 16; ++j) rs[j] = 0.f;

    if (J >= 2 * I + 2) {
#pragma unroll
        for (int mt = 0; mt < 4; ++mt)
#pragma unroll
            for (int nt = 0; nt < 4; ++nt)
#pragma unroll
                for (int r = 0; r < 4; ++r) {
                    float e = __expf(2.f * acc[mt][nt][r]);
                    rs[mt * 4 + r] += e;
                    cs[nt] += e;
                }
        if (J >= 32 && ((J - 32) >> 1) == I) {
#pragma unroll
            for (int mt = 0; mt < 4; ++mt)
#pragma unroll
                for (int nt = 0; nt < 4; ++nt) {
                    int gcol = n0 + wcol + nt * 16 + lane15;
#pragma unroll
                    for (int r = 0; r < 4; ++r) {
                        int grow = m0 + wrow + mt * 16 + quad * 4 + r;
                        if (gcol == grow + N_ROWS) {
                            float s = acc[mt][nt][r];
                            cdp[grow] = s;
                            cdp[gcol] = s;
                        }
                    }
                }
        }
    } else {
#pragma unroll
        for (int mt = 0; mt < 4; ++mt)
#pragma unroll
            for (int nt = 0; nt < 4; ++nt) {
                int gcol = n0 + wcol + nt * 16 + lane15;
#pragma unroll
                for (int r = 0; r < 4; ++r) {
                    int grow = m0 + wrow + mt * 16 + quad * 4 + r;
                    if (grow < gcol) {
                        float e = __expf(2.f * acc[mt][nt][r]);
                        rs[mt * 4 + r] += e;
                        cs[nt] += e;
                    }
                }
            }
    }

#pragma unroll
    for (int j = 0; j < 16; ++j) {
        float v = rs[j];
        v += __shfl_xor(v, 1); v += __shfl_xor(v, 2);
        v += __shfl_xor(v, 4); v += __shfl_xor(v, 8);
        rs[j] = v;
    }
    if (lane15 == 0) {
#pragma unroll
        for (int j = 0; j < 16; ++j) {
            int grow = m0 + wrow + (j >> 2) * 16 + quad * 4 + (j & 3);
            atomicAdd(&rp[grow], rs[j]);
        }
    }
#pragma unroll
    for (int n = 0; n < 4; ++n) {
        float v = cs[n];
        v += __shfl_xor(v, 16); v += __shfl_xor(v, 32);
        cs[n] = v;
    }
    if (quad == 0) {
#pragma unroll
        for (int n = 0; n < 4; ++n) {
            int gcol = n0 + wcol + n * 16 + lane15;
            atomicAdd(&rp[gcol], cs[n]);
        }
    }
}

// ---------------- final loss reduction ----------------
__global__ void loss_kernel(const float* __restrict__ rowsum,
                            const float* __restrict__ crossdot, float* __restrict__ out) {
    __shared__ float red[256];
    float acc = 0.f;
    for (int i = threadIdx.x; i < 3 * 2 * N_ROWS; i += 256) {
        acc += logf(rowsum[i]) - 2.f * crossdot[i];
    }
    red[threadIdx.x] = acc;
    __syncthreads();
    for (int s = 128; s > 0; s >>= 1) {
        if (threadIdx.x < s) red[threadIdx.x] += red[threadIdx.x + s];
        __syncthreads();
    }
    if (threadIdx.x == 0) out[0] = red[0] * (1.f / 24576.f);
}

// ---------------- launch ----------------
extern "C" void kernel_launch(void* const* d_in, const int* in_sizes, int n_in,
                              void* d_out, int out_size, void* d_ws, size_t ws_size,
                              hipStream_t stream) {
    const float* doc0   = (const float*)d_in[0];
    const float* doc1   = (const float*)d_in[1];
    const float* doc2   = (const float*)d_in[2];
    const float* W1s    = (const float*)d_in[3];
    const float* b1s    = (const float*)d_in[4];
    const float* gammas = (const float*)d_in[5];
    const float* betas  = (const float*)d_in[6];
    const float* W2s    = (const float*)d_in[7];
    const float* b2s    = (const float*)d_in[8];
    float* out = (float*)d_out;

    char* base = (char*)d_ws;
    size_t off = 0;
    auto alloc = [&](size_t bytes) -> char* {
        char* r = base + off;
        off += (bytes + 255) & ~(size_t)255;
        return r;
    };

    unsigned short* Xb   = (unsigned short*)alloc((size_t)3 * N_ROWS * IN_DIM * 2);
    unsigned short* W1t  = (unsigned short*)alloc((size_t)6 * OUT_DIM * IN_DIM * 2);
    unsigned short* W2t  = (unsigned short*)alloc((size_t)6 * OUT_DIM * OUT_DIM * 2);
    unsigned short* H    = (unsigned short*)alloc((size_t)6 * N_ROWS * OUT_DIM * 2);
    unsigned short* Hb   = (unsigned short*)alloc((size_t)6 * N_ROWS * OUT_DIM * 2);
    unsigned char*  Abuf = (unsigned char*)Xb;    // Xb dead after gemm1
    char* zbase = alloc(24576 + 98304);
    float* stats  = (float*)zbase;
    float* rowsum = (float*)(zbase + 24576);
    float* cdot   = (float*)alloc((size_t)3 * 2 * N_ROWS * 4);

    if (ws_size < off) return;

    // 26112 conversion wave-units + 120 zero units = 26232 -> 6558 blocks
    prep<<<6558, 256, 0, stream>>>(doc0, doc1, doc2, W1s, W2s, Xb, W1t, W2t, zbase);

    gemm1_bn<<<dim3(OUT_DIM / 128, N_ROWS / 256, 6), 512, 0, stream>>>(Xb, W1t, b1s, H, stats);

    bn_apply<<<6144, 256, 0, stream>>>(H, Hb, stats, gammas, betas);

    gemm2_fused<<<dim3(64, 6), 512, 0, stream>>>(Hb, W2t, b2s, Abuf);

    // supertile gram: 3 pairs x 1056 (J>=2I) tile-pairs, XCD swizzled
    gram_kernel<<<3168, 512, 0, stream>>>(Abuf, rowsum, cdot);

    loss_kernel<<<1, 256, 0, stream>>>(rowsum, cdot, out);
}

// Round 13
// 287.242 us; speedup vs baseline: 1.2631x; 1.1510x over previous
//
#include <hip/hip_runtime.h>
#include <hip/hip_bf16.h>
#include <hip/hip_fp8.h>

#define N_ROWS 4096
#define IN_DIM 768
#define OUT_DIM 512

// All GEMM operands fragment-major, all K-loops barrier-free (no LDS staging).
// Fragment-major (R rows, K cols): unit = gt*(K/32)+kf (gt=row>>4, kf=k>>5),
// byte addr = (unit*64+lane)*16; lane elems: row = gt*16+(lane&15),
// k = kf*32+(lane>>4)*8+j. bf16: 8 elems/lane; fp8: 16 = 2 frags (lo=even kf).
// R13: XCD-contiguous grids for gemm1/gemm2 (A m-tiles + B stay L2-resident
// per XCD; gemm1 HBM traffic ~220->~45 MB) and parallel loss reduction
// (1 block -> 96 blocks + atomicAdd). Everything else identical to R12.

using bf16x8 = __attribute__((ext_vector_type(8))) short;
using f32x4  = __attribute__((ext_vector_type(4))) float;
using i64    = long;
using i64x2  = __attribute__((ext_vector_type(2))) long;

__device__ __constant__ int c_docmap[6] = {0, 1, 0, 2, 1, 2};

__device__ inline unsigned short f2bf(float f) {
    __hip_bfloat16 h = __float2bfloat16(f);
    return reinterpret_cast<unsigned short&>(h);
}
__device__ inline float bf2f(unsigned short u) {
    return __uint_as_float((unsigned int)u << 16);
}
__device__ inline unsigned char f2fp8(float f) {
    __hip_fp8_e4m3 t(f);           // OCP e4m3fn, RNE+sat
    return t.__x;
}
__device__ inline uint4 pack8bf(const float* v) {
    uint4 o;
    unsigned short* p = (unsigned short*)&o;
#pragma unroll
    for (int j = 0; j < 8; ++j) p[j] = f2bf(v[j]);
    return o;
}

// ---------------- prep: conversions to fragment-major + zero-init ----------------
__global__ __launch_bounds__(256) void prep(
    const float* __restrict__ d0, const float* __restrict__ d1,
    const float* __restrict__ d2, const float* __restrict__ W1s,
    const float* __restrict__ W2s, unsigned short* __restrict__ Xb,
    unsigned short* __restrict__ W1t, unsigned short* __restrict__ W2t,
    char* __restrict__ zbase) {
    int wunit = blockIdx.x * 4 + (threadIdx.x >> 6);
    int lane = threadIdx.x & 63;
    int lane15 = lane & 15, quad = lane >> 4;
    if (wunit < 18432) {
        int d = wunit / 6144, u = wunit % 6144;       // 256 gt x 24 kf
        int gt = u / 24, kf = u % 24;
        const float* src = (d == 0) ? d0 : ((d == 1) ? d1 : d2);
        const float* s = src + (size_t)(gt * 16 + lane15) * IN_DIM + kf * 32 + quad * 8;
        float4 a = *(const float4*)s, b = *(const float4*)(s + 4);
        float v[8] = {a.x, a.y, a.z, a.w, b.x, b.y, b.z, b.w};
        *(uint4*)(Xb + (size_t)d * N_ROWS * IN_DIM + (size_t)u * 512 + lane * 8) = pack8bf(v);
    } else if (wunit < 23040) {
        int v0 = wunit - 18432;
        int z = v0 / 768, u = v0 % 768;               // 32 gt x 24 kf
        int gt = u / 24, kf = u % 24;
        int n = gt * 16 + lane15;
        int k0 = kf * 32 + quad * 8;
        const float* W = W1s + (size_t)z * IN_DIM * OUT_DIM;
        float v[8];
#pragma unroll
        for (int j = 0; j < 8; ++j) v[j] = W[(size_t)(k0 + j) * OUT_DIM + n];
        *(uint4*)(W1t + (size_t)z * OUT_DIM * IN_DIM + (size_t)u * 512 + lane * 8) = pack8bf(v);
    } else if (wunit < 26112) {
        int v0 = wunit - 23040;
        int z = v0 / 512, u = v0 % 512;               // 32 gt x 16 kf
        int gt = u / 16, kf = u % 16;
        int n = gt * 16 + lane15;
        int k0 = kf * 32 + quad * 8;
        const float* W = W2s + (size_t)z * OUT_DIM * OUT_DIM;
        float v[8];
#pragma unroll
        for (int j = 0; j < 8; ++j) v[j] = W[(size_t)(k0 + j) * OUT_DIM + n];
        *(uint4*)(W2t + (size_t)z * OUT_DIM * OUT_DIM + (size_t)u * 512 + lane * 8) = pack8bf(v);
    } else {
        size_t b = (size_t)(wunit - 26112) * 1024 + (size_t)lane * 16;
        if (b < (size_t)(24576 + 98304))
            *(float4*)(zbase + b) = (float4){0.f, 0.f, 0.f, 0.f};
    }
}

// ---------------- GEMM1: 256x128 supertile, barrier-free, BF16 out + BN-stats ----------------
// 1D grid 384, XCD-contiguous: xcd = px&7 gets 48 consecutive logical blocks
// (z-major, n innermost) -> A m-tile reused across its 4 n-blocks in L2.
__global__ __launch_bounds__(512) void gemm1_bn(
    const unsigned short* __restrict__ Xb, const unsigned short* __restrict__ W1t,
    const float* __restrict__ biasAll, unsigned short* __restrict__ H,
    float* __restrict__ stats) {
    const int NKF = IN_DIM / 32;   // 24
    int px = blockIdx.x;
    int L = (px & 7) * 48 + (px >> 3);            // 384 = 8 * 48
    int z = L >> 6, rem = L & 63;
    int m0 = (rem >> 2) * 256, n0 = (rem & 3) * 128;
    const unsigned short* A = Xb + (size_t)c_docmap[z] * N_ROWS * IN_DIM;
    const unsigned short* B = W1t + (size_t)z * OUT_DIM * IN_DIM;
    const float* bz = biasAll + (size_t)z * OUT_DIM;
    unsigned short* C = H + (size_t)z * N_ROWS * OUT_DIM;

    int tid = threadIdx.x;
    int wave = tid >> 6, lane = tid & 63;
    int lane15 = lane & 15, quad = lane >> 4;
    int wrow = (wave >> 1) * 64, wcol = (wave & 1) * 64;

    const unsigned short* Ca = A + (size_t)((m0 + wrow) >> 4) * NKF * 512 + (size_t)lane * 8;
    const unsigned short* Cb = B + (size_t)((n0 + wcol) >> 4) * NKF * 512 + (size_t)lane * 8;

    f32x4 acc[4][4];
#pragma unroll
    for (int mt = 0; mt < 4; ++mt)
#pragma unroll
        for (int nt = 0; nt < 4; ++nt)
            acc[mt][nt] = (f32x4){0.f, 0.f, 0.f, 0.f};

    bf16x8 aC[4], bC[4], aN[4], bN[4];
#pragma unroll
    for (int t = 0; t < 4; ++t) {
        aC[t] = *(const bf16x8*)(Ca + (size_t)t * NKF * 512);
        bC[t] = *(const bf16x8*)(Cb + (size_t)t * NKF * 512);
    }
#pragma unroll
    for (int kf = 0; kf < NKF; ++kf) {
        if (kf < NKF - 1) {
#pragma unroll
            for (int t = 0; t < 4; ++t) {
                aN[t] = *(const bf16x8*)(Ca + (size_t)t * NKF * 512 + (kf + 1) * 512);
                bN[t] = *(const bf16x8*)(Cb + (size_t)t * NKF * 512 + (kf + 1) * 512);
            }
        }
#pragma unroll
        for (int mt = 0; mt < 4; ++mt)
#pragma unroll
            for (int nt = 0; nt < 4; ++nt)
                acc[mt][nt] = __builtin_amdgcn_mfma_f32_16x16x32_bf16(aC[mt], bC[nt], acc[mt][nt], 0, 0, 0);
#pragma unroll
        for (int t = 0; t < 4; ++t) { aC[t] = aN[t]; bC[t] = bN[t]; }
    }

    float s1[4] = {0.f, 0.f, 0.f, 0.f}, s2[4] = {0.f, 0.f, 0.f, 0.f};
#pragma unroll
    for (int nt = 0; nt < 4; ++nt) {
        int col = n0 + wcol + nt * 16 + lane15;
        float bv = bz[col];
#pragma unroll
        for (int mt = 0; mt < 4; ++mt)
#pragma unroll
            for (int r = 0; r < 4; ++r) {
                int row = m0 + wrow + mt * 16 + quad * 4 + r;
                float v = acc[mt][nt][r] + bv;
                C[(size_t)row * OUT_DIM + col] = f2bf(v);
                s1[nt] += v; s2[nt] += v * v;       // stats from fp32 (exact)
            }
    }
#pragma unroll
    for (int nt = 0; nt < 4; ++nt) {
        float a = s1[nt], b = s2[nt];
        a += __shfl_xor(a, 16); a += __shfl_xor(a, 32);
        b += __shfl_xor(b, 16); b += __shfl_xor(b, 32);
        if (quad == 0) {
            int col = n0 + wcol + nt * 16 + lane15;
            atomicAdd(&stats[((size_t)z * OUT_DIM + col) * 2 + 0], a);
            atomicAdd(&stats[((size_t)z * OUT_DIM + col) * 2 + 1], b);
        }
    }
}

// ---------------- BN apply + ReLU: bf16 H row-major -> bf16 Hb FRAG-MAJOR ----------------
__global__ __launch_bounds__(256) void bn_apply(
    const unsigned short* __restrict__ H, unsigned short* __restrict__ Hb,
    const float* __restrict__ stats, const float* __restrict__ gammas,
    const float* __restrict__ betas) {
    int wunit = blockIdx.x * 4 + (threadIdx.x >> 6);
    if (wunit >= 24576) return;
    int lane = threadIdx.x & 63;
    int lane15 = lane & 15, quad = lane >> 4;
    int z = wunit / 4096, u = wunit % 4096;       // 256 gt x 16 kf
    int gt = u / 16, kf = u % 16;
    int row = gt * 16 + lane15;
    int k = kf * 32 + quad * 8;
    uint4 hu = *(const uint4*)(H + ((size_t)z * N_ROWS + row) * OUT_DIM + k);
    unsigned int w[4] = {hu.x, hu.y, hu.z, hu.w};
    float v[8];
#pragma unroll
    for (int j = 0; j < 8; ++j) {
        unsigned short us = (j & 1) ? (unsigned short)(w[j >> 1] >> 16)
                                    : (unsigned short)(w[j >> 1] & 0xffff);
        size_t sc = (size_t)z * OUT_DIM + k + j;
        float mu = stats[sc * 2 + 0] * (1.f / N_ROWS);
        float var = stats[sc * 2 + 1] * (1.f / N_ROWS) - mu * mu;
        float s = gammas[sc] * rsqrtf(var + 1e-5f);
        v[j] = fmaxf(fmaf(bf2f(us), s, betas[sc] - mu * s), 0.f);
    }
    *(uint4*)(Hb + (size_t)z * N_ROWS * OUT_DIM + (size_t)u * 512 + lane * 8) = pack8bf(v);
}

// ---------------- GEMM2 fused: barrier-free K-loop + l2norm/fp8/transpose epilogue ----------------
// 64 rows x 512 cols per block. 1D grid 384, XCD-contiguous (z-major):
// each XCD covers mostly one z -> W2 slab L2-resident.
__global__ __launch_bounds__(512) void gemm2_fused(
    const unsigned short* __restrict__ Hb, const unsigned short* __restrict__ W2t,
    const float* __restrict__ biasAll, unsigned char* __restrict__ Abuf) {
    const int NKF = OUT_DIM / 32;  // 16
    int px = blockIdx.x;
    int L = (px & 7) * 48 + (px >> 3);            // 384 = 8 * 48
    int z = L >> 6;
    int m0 = (L & 63) * 64;
    const unsigned short* A = Hb + (size_t)z * N_ROWS * OUT_DIM;
    const unsigned short* B = W2t + (size_t)z * OUT_DIM * OUT_DIM;
    const float* bz = biasAll + (size_t)z * OUT_DIM;
    unsigned char* Az = Abuf + (size_t)z * N_ROWS * OUT_DIM;

    int tid = threadIdx.x;
    int wave = tid >> 6, lane = tid & 63;
    int lane15 = lane & 15, quad = lane >> 4;
    int wcol = wave * 64;

    const unsigned short* Ca = A + (size_t)(m0 >> 4) * NKF * 512 + (size_t)lane * 8;
    const unsigned short* Cb = B + (size_t)(wave * 4) * NKF * 512 + (size_t)lane * 8;

    f32x4 acc[4][4];
#pragma unroll
    for (int mt = 0; mt < 4; ++mt)
#pragma unroll
        for (int nt = 0; nt < 4; ++nt)
            acc[mt][nt] = (f32x4){0.f, 0.f, 0.f, 0.f};

    bf16x8 aC[4], bC[4], aN[4], bN[4];
#pragma unroll
    for (int t = 0; t < 4; ++t) {
        aC[t] = *(const bf16x8*)(Ca + (size_t)t * NKF * 512);
        bC[t] = *(const bf16x8*)(Cb + (size_t)t * NKF * 512);
    }
#pragma unroll
    for (int kf = 0; kf < NKF; ++kf) {
        if (kf < NKF - 1) {
#pragma unroll
            for (int t = 0; t < 4; ++t) {
                aN[t] = *(const bf16x8*)(Ca + (size_t)t * NKF * 512 + (kf + 1) * 512);
                bN[t] = *(const bf16x8*)(Cb + (size_t)t * NKF * 512 + (kf + 1) * 512);
            }
        }
#pragma unroll
        for (int mt = 0; mt < 4; ++mt)
#pragma unroll
            for (int nt = 0; nt < 4; ++nt)
                acc[mt][nt] = __builtin_amdgcn_mfma_f32_16x16x32_bf16(aC[mt], bC[nt], acc[mt][nt], 0, 0, 0);
#pragma unroll
        for (int t = 0; t < 4; ++t) { aC[t] = aN[t]; bC[t] = bN[t]; }
    }

    // ---- epilogue (validated R11/R12): bias, row sumsq, normalize, fp8, transpose ----
    __shared__ float part[8][64];
    __shared__ float scf[64];
    __shared__ __attribute__((aligned(16))) unsigned char T[64 * 520];

    float rs[16];
#pragma unroll
    for (int j = 0; j < 16; ++j) rs[j] = 0.f;
#pragma unroll
    for (int nt = 0; nt < 4; ++nt) {
        float bv = bz[wcol + nt * 16 + lane15];
#pragma unroll
        for (int mt = 0; mt < 4; ++mt)
#pragma unroll
            for (int r = 0; r < 4; ++r) {
                float v = acc[mt][nt][r] + bv;
                acc[mt][nt][r] = v;
                rs[mt * 4 + r] += v * v;
            }
    }
#pragma unroll
    for (int j = 0; j < 16; ++j) {
        float v = rs[j];
        v += __shfl_xor(v, 1); v += __shfl_xor(v, 2);
        v += __shfl_xor(v, 4); v += __shfl_xor(v, 8);
        rs[j] = v;
    }
    if (lane15 == 0) {
#pragma unroll
        for (int j = 0; j < 16; ++j)
            part[wave][(j >> 2) * 16 + quad * 4 + (j & 3)] = rs[j];
    }
    __syncthreads();
    if (tid < 64) {
        float ss = 0.f;
#pragma unroll
        for (int w = 0; w < 8; ++w) ss += part[w][tid];
        scf[tid] = 1.f / fmaxf(sqrtf(ss), 1e-12f);
    }
    __syncthreads();
#pragma unroll
    for (int mt = 0; mt < 4; ++mt)
#pragma unroll
        for (int r = 0; r < 4; ++r) {
            int row = mt * 16 + quad * 4 + r;
            float s = scf[row];
#pragma unroll
            for (int nt = 0; nt < 4; ++nt)
                T[row * 520 + wcol + nt * 16 + lane15] = f2fp8(acc[mt][nt][r] * s);
        }
    __syncthreads();
    // readback A-frag-major: wave = kh, lane's 16 B = frags kf=2kh (lo), 2kh+1 (hi)
#pragma unroll
    for (int gt = 0; gt < 4; ++gt) {
        int row = gt * 16 + lane15;
        i64 lo = *(const i64*)(T + row * 520 + (2 * wave) * 32 + quad * 8);
        i64 hi = *(const i64*)(T + row * 520 + (2 * wave + 1) * 32 + quad * 8);
        i64x2 st; st[0] = lo; st[1] = hi;
        int gtg = (m0 >> 4) + gt;
        *(i64x2*)(Az + ((size_t)(gtg * 8 + wave) * 64 + lane) * 16) = st;
    }
}

// ---------------- barrier-free fp8 Gram: 256x128 supertile, J>=2I masked ----------------
__global__ __launch_bounds__(512) void gram_kernel(const unsigned char* __restrict__ Abase,
                                                   float* __restrict__ rowsum,
                                                   float* __restrict__ crossdot) {
    int px = blockIdx.x;
    int logical = (px & 7) * 396 + (px >> 3);     // 3168 = 8 * 396
    int p = logical / 1056;
    int t0 = logical - p * 1056;
    const unsigned char* Cm = Abase + (size_t)p * 2 * N_ROWS * OUT_DIM;

    int I = 0;
    while (t0 >= 64 - 2 * I) { t0 -= 64 - 2 * I; ++I; }
    int J = 2 * I + t0;
    int m0 = I * 256, n0 = J * 128;

    int tid = threadIdx.x;
    int wave = tid >> 6, lane = tid & 63;
    int lane15 = lane & 15, quad = lane >> 4;
    int wrow = (wave >> 1) * 64, wcol = (wave & 1) * 64;

    const unsigned char* Ca = Cm + (size_t)((m0 + wrow) >> 4) * 8192 + (size_t)lane * 16;
    const unsigned char* Cb = Cm + (size_t)((n0 + wcol) >> 4) * 8192 + (size_t)lane * 16;

    f32x4 acc[4][4];
#pragma unroll
    for (int mt = 0; mt < 4; ++mt)
#pragma unroll
        for (int nt = 0; nt < 4; ++nt)
            acc[mt][nt] = (f32x4){0.f, 0.f, 0.f, 0.f};

    i64x2 aC[4], bC[4], aN[4], bN[4];
#pragma unroll
    for (int t = 0; t < 4; ++t) {
        aC[t] = *(const i64x2*)(Ca + (size_t)t * 8192);
        bC[t] = *(const i64x2*)(Cb + (size_t)t * 8192);
    }
#pragma unroll
    for (int kh = 0; kh < 8; ++kh) {
        if (kh < 7) {
#pragma unroll
            for (int t = 0; t < 4; ++t) {
                aN[t] = *(const i64x2*)(Ca + (size_t)t * 8192 + (kh + 1) * 1024);
                bN[t] = *(const i64x2*)(Cb + (size_t)t * 8192 + (kh + 1) * 1024);
            }
        }
#pragma unroll
        for (int half = 0; half < 2; ++half)
#pragma unroll
            for (int mt = 0; mt < 4; ++mt)
#pragma unroll
                for (int nt = 0; nt < 4; ++nt)
                    acc[mt][nt] = __builtin_amdgcn_mfma_f32_16x16x32_fp8_fp8(
                        aC[mt][half], bC[nt][half], acc[mt][nt], 0, 0, 0);
#pragma unroll
        for (int t = 0; t < 4; ++t) { aC[t] = aN[t]; bC[t] = bN[t]; }
    }

    float* cdp = crossdot + (size_t)p * 2 * N_ROWS;
    float* rp  = rowsum  + (size_t)p * 2 * N_ROWS;

    float rs[16];
    float cs[4] = {0.f, 0.f, 0.f, 0.f};
#pragma unroll
    for (int j = 0; j < 16; ++j) rs[j] = 0.f;

    if (J >= 2 * I + 2) {
#pragma unroll
        for (int mt = 0; mt < 4; ++mt)
#pragma unroll
            for (int nt = 0; nt < 4; ++nt)
#pragma unroll
                for (int r = 0; r < 4; ++r) {
                    float e = __expf(2.f * acc[mt][nt][r]);
                    rs[mt * 4 + r] += e;
                    cs[nt] += e;
                }
        if (J >= 32 && ((J - 32) >> 1) == I) {
#pragma unroll
            for (int mt = 0; mt < 4; ++mt)
#pragma unroll
                for (int nt = 0; nt < 4; ++nt) {
                    int gcol = n0 + wcol + nt * 16 + lane15;
#pragma unroll
                    for (int r = 0; r < 4; ++r) {
                        int grow = m0 + wrow + mt * 16 + quad * 4 + r;
                        if (gcol == grow + N_ROWS) {
                            float s = acc[mt][nt][r];
                            cdp[grow] = s;
                            cdp[gcol] = s;
                        }
                    }
                }
        }
    } else {
#pragma unroll
        for (int mt = 0; mt < 4; ++mt)
#pragma unroll
            for (int nt = 0; nt < 4; ++nt) {
                int gcol = n0 + wcol + nt * 16 + lane15;
#pragma unroll
                for (int r = 0; r < 4; ++r) {
                    int grow = m0 + wrow + mt * 16 + quad * 4 + r;
                    if (grow < gcol) {
                        float e = __expf(2.f * acc[mt][nt][r]);
                        rs[mt * 4 + r] += e;
                        cs[nt] += e;
                    }
                }
            }
    }

#pragma unroll
    for (int j = 0; j < 16; ++j) {
        float v = rs[j];
        v += __shfl_xor(v, 1); v += __shfl_xor(v, 2);
        v += __shfl_xor(v, 4); v += __shfl_xor(v, 8);
        rs[j] = v;
    }
    if (lane15 == 0) {
#pragma unroll
        for (int j = 0; j < 16; ++j) {
            int grow = m0 + wrow + (j >> 2) * 16 + quad * 4 + (j & 3);
            atomicAdd(&rp[grow], rs[j]);
        }
    }
#pragma unroll
    for (int n = 0; n < 4; ++n) {
        float v = cs[n];
        v += __shfl_xor(v, 16); v += __shfl_xor(v, 32);
        cs[n] = v;
    }
    if (quad == 0) {
#pragma unroll
        for (int n = 0; n < 4; ++n) {
            int gcol = n0 + wcol + n * 16 + lane15;
            atomicAdd(&rp[gcol], cs[n]);
        }
    }
}

// ---------------- final loss reduction: 96 blocks + device atomic ----------------
__global__ void loss_kernel(const float* __restrict__ rowsum,
                            const float* __restrict__ crossdot, float* __restrict__ out) {
    int i = blockIdx.x * 256 + threadIdx.x;       // 96*256 = 24576 exactly
    float v = logf(rowsum[i]) - 2.f * crossdot[i];
#pragma unroll
    for (int m = 1; m < 64; m <<= 1) v += __shfl_xor(v, m);
    __shared__ float red[4];
    if ((threadIdx.x & 63) == 0) red[threadIdx.x >> 6] = v;
    __syncthreads();
    if (threadIdx.x == 0)
        atomicAdd(out, (red[0] + red[1] + red[2] + red[3]) * (1.f / 24576.f));
}

// ---------------- launch ----------------
extern "C" void kernel_launch(void* const* d_in, const int* in_sizes, int n_in,
                              void* d_out, int out_size, void* d_ws, size_t ws_size,
                              hipStream_t stream) {
    const float* doc0   = (const float*)d_in[0];
    const float* doc1   = (const float*)d_in[1];
    const float* doc2   = (const float*)d_in[2];
    const float* W1s    = (const float*)d_in[3];
    const float* b1s    = (const float*)d_in[4];
    const float* gammas = (const float*)d_in[5];
    const float* betas  = (const float*)d_in[6];
    const float* W2s    = (const float*)d_in[7];
    const float* b2s    = (const float*)d_in[8];
    float* out = (float*)d_out;

    char* base = (char*)d_ws;
    size_t off = 0;
    auto alloc = [&](size_t bytes) -> char* {
        char* r = base + off;
        off += (bytes + 255) & ~(size_t)255;
        return r;
    };

    unsigned short* Xb   = (unsigned short*)alloc((size_t)3 * N_ROWS * IN_DIM * 2);
    unsigned short* W1t  = (unsigned short*)alloc((size_t)6 * OUT_DIM * IN_DIM * 2);
    unsigned short* W2t  = (unsigned short*)alloc((size_t)6 * OUT_DIM * OUT_DIM * 2);
    unsigned short* H    = (unsigned short*)alloc((size_t)6 * N_ROWS * OUT_DIM * 2);
    unsigned short* Hb   = (unsigned short*)alloc((size_t)6 * N_ROWS * OUT_DIM * 2);
    unsigned char*  Abuf = (unsigned char*)Xb;    // Xb dead after gemm1
    char* zbase = alloc(24576 + 98304);
    float* stats  = (float*)zbase;
    float* rowsum = (float*)(zbase + 24576);
    float* cdot   = (float*)alloc((size_t)3 * 2 * N_ROWS * 4);

    if (ws_size < off) return;

    hipMemsetAsync(out, 0, sizeof(float), stream);   // loss accumulates atomically

    // 26112 conversion wave-units + 120 zero units = 26232 -> 6558 blocks
    prep<<<6558, 256, 0, stream>>>(doc0, doc1, doc2, W1s, W2s, Xb, W1t, W2t, zbase);

    gemm1_bn<<<384, 512, 0, stream>>>(Xb, W1t, b1s, H, stats);

    bn_apply<<<6144, 256, 0, stream>>>(H, Hb, stats, gammas, betas);

    gemm2_fused<<<384, 512, 0, stream>>>(Hb, W2t, b2s, Abuf);

    // supertile gram: 3 pairs x 1056 (J>=2I) tile-pairs, XCD swizzled
    gram_kernel<<<3168, 512, 0, stream>>>(Abuf, rowsum, cdot);

    loss_kernel<<<96, 256, 0, stream>>>(rowsum, cdot, out);
}